// Round 3
// baseline (27020.590 us; speedup 1.0000x reference)
//
#include <hip/hip_runtime.h>
#include <hip/hip_cooperative_groups.h>

namespace cg = cooperative_groups;

typedef unsigned short u16;
typedef __attribute__((ext_vector_type(8))) __bf16 bf16x8;
typedef __attribute__((ext_vector_type(4))) float f32x4;

#define T_SEQ 256
#define N_B   1024
#define C_IN  128
#define H_DIM 512
#define NCLS  40
#define NT0   20
#define NT1   32
#define HSLOT (16*1024*32)   // u16 elems per hpack slot

union B8 { bf16x8 v; u16 s[8]; };

// ---------- bf16 split helpers ----------
__device__ __forceinline__ u16 f32_to_bf16_rne(float x) {
    unsigned u = __float_as_uint(x);
    unsigned rounding = 0x7FFFu + ((u >> 16) & 1u);
    return (u16)((u + rounding) >> 16);
}
__device__ __forceinline__ float bf16_to_f32(u16 h) {
    return __uint_as_float(((unsigned)h) << 16);
}
__device__ __forceinline__ void split2(float x, u16& hi, u16& lo) {
    u16 h = f32_to_bf16_rne(x);
    float hf = bf16_to_f32(h);
    u16 l = f32_to_bf16_rne(x - hf);
    hi = h; lo = l;
}
__device__ __forceinline__ float fast_sigmoid(float x) {
    return 1.0f / (1.0f + __expf(-x));
}
__device__ __forceinline__ float fast_tanh(float x) {
    return 1.0f - 2.0f / (__expf(2.0f * x) + 1.0f);
}

// ---------- prep: pack W into per-(ct,kt) fragment blocks ----------
// layout: idx = ((ct*NT + kt)*128 + r)*32 + k ; r = 4*jl + gate
__global__ void k_pack_w(const float* __restrict__ Wih, const float* __restrict__ Whh,
                         int KX, int NT, u16* __restrict__ hi, u16* __restrict__ lo) {
    size_t idx = (size_t)blockIdx.x * 256 + threadIdx.x;
    size_t total = (size_t)16 * NT * 128 * 32;
    if (idx >= total) return;
    int k = (int)(idx & 31);
    int r = (int)((idx >> 5) & 127);
    int rem = (int)(idx >> 12);
    int kt = rem % NT, ct = rem / NT;
    int gate = r & 3, jl = r >> 2;
    int srow = (gate << 9) + (ct << 5) + jl;
    int kg = (kt << 5) + k;
    float v = (kg < KX) ? Wih[(size_t)srow * KX + kg] : Whh[(size_t)srow * H_DIM + (kg - KX)];
    u16 h, l; split2(v, h, l);
    hi[idx] = h; lo[idx] = l;
}

// ---------- LSTM step tile body ----------
// block = 128 batch x 128 G'-cols, 8 waves.
// BK=64 super-steps: waves 0-3 (grp 0) compute even k-tiles, waves 4-7 (grp 1)
// odd k-tiles; each wave owns a 64x64 output tile (4x4 acc).  Partial sums are
// reduced through two 64KB G' halves in LDS at the end.
// c-state lives in 8 registers per thread (persistent block identity).
__device__ __forceinline__ void lstm_tile_body(
    int ct, int n0,
    const float* __restrict__ Xf32,                       // L0: data + t*C (row stride 32768), else null
    const u16* __restrict__ xAhi, const u16* __restrict__ xAlo, int nxt,
    const u16* __restrict__ hAhi, const u16* __restrict__ hAlo,
    const u16* __restrict__ Whi, const u16* __restrict__ Wlo, int NT,
    float* __restrict__ creg,
    u16* __restrict__ oHhi, u16* __restrict__ oHlo, float* __restrict__ oF32,
    char* lds, const float* biasT)
{
    int tid  = threadIdx.x;
    int w    = tid >> 6;
    int l    = tid & 63;
    int quad = l >> 4;
    int lr   = l & 15;
    int grp  = w >> 2;              // 0: even k-tiles, 1: odd k-tiles
    int wr   = (w & 1) << 6;        // 0 or 64
    int wc2  = ((w >> 1) & 1) << 6; // 0 or 64

    const size_t wbase = ((size_t)(ct * NT)) << 12;
    bf16x8 sa_h[2], sa_l[2], sb_h[2], sb_l[2];

    auto load_stage = [&](int ss) {
        #pragma unroll
        for (int g = 0; g < 2; g++) {
            int kt = (ss << 1) | g;
            size_t wo = wbase + ((size_t)kt << 12) + ((size_t)tid << 3);
            sb_h[g] = *(const bf16x8*)(Whi + wo);
            sb_l[g] = *(const bf16x8*)(Wlo + wo);
            if (Xf32 != nullptr && kt < nxt) {
                int row = tid >> 2, seg = tid & 3;
                const float* p = Xf32 + (size_t)(n0 + row) * 32768 + (kt << 5) + (seg << 3);
                f32x4 x0 = *(const f32x4*)p;
                f32x4 x1 = *(const f32x4*)(p + 4);
                B8 hh, ll;
                #pragma unroll
                for (int e = 0; e < 4; e++) { u16 a, b; split2(x0[e], a, b); hh.s[e] = a; ll.s[e] = b; }
                #pragma unroll
                for (int e = 0; e < 4; e++) { u16 a, b; split2(x1[e], a, b); hh.s[4 + e] = a; ll.s[4 + e] = b; }
                sa_h[g] = hh.v; sa_l[g] = ll.v;
            } else {
                const u16 *ph, *pl; int kk;
                if (kt < nxt) { ph = xAhi; pl = xAlo; kk = kt; }
                else          { ph = hAhi; pl = hAlo; kk = kt - nxt; }
                size_t ao = (((size_t)kk * 1024 + n0) << 5) + ((size_t)tid << 3);
                sa_h[g] = *(const bf16x8*)(ph + ao);
                sa_l[g] = *(const bf16x8*)(pl + ao);
            }
        }
    };
    auto write_stage = [&](char* buf) {
        #pragma unroll
        for (int g = 0; g < 2; g++) {
            char* p = buf + (g << 13) + (tid << 4);
            *(bf16x8*)(p)          = sa_h[g];
            *(bf16x8*)(p + 16384)  = sa_l[g];
            *(bf16x8*)(p + 32768)  = sb_h[g];
            *(bf16x8*)(p + 49152)  = sb_l[g];
        }
    };

    f32x4 acc[4][4];
    #pragma unroll
    for (int i = 0; i < 4; i++)
        #pragma unroll
        for (int j = 0; j < 4; j++)
            acc[i][j] = (f32x4){0.f, 0.f, 0.f, 0.f};

    const int NS = NT >> 1;
    load_stage(0);
    write_stage(lds);
    __syncthreads();

    for (int ss = 0; ss < NS; ss++) {
        char* cur = lds + ((ss & 1) << 16) + (grp << 13);
        if (ss + 1 < NS) load_stage(ss + 1);

        bf16x8 ah[4], al[4];
        #pragma unroll
        for (int i = 0; i < 4; i++) {
            int ro = ((wr + (i << 4) + lr) << 6) + (quad << 4);
            ah[i] = *(const bf16x8*)(cur + ro);
            al[i] = *(const bf16x8*)(cur + 16384 + ro);
        }
        #pragma unroll
        for (int jp = 0; jp < 2; jp++) {
            bf16x8 bh[2], bl[2];
            #pragma unroll
            for (int u = 0; u < 2; u++) {
                int j = (jp << 1) | u;
                int ro = ((wc2 + (j << 4) + lr) << 6) + (quad << 4);
                bh[u] = *(const bf16x8*)(cur + 32768 + ro);
                bl[u] = *(const bf16x8*)(cur + 49152 + ro);
            }
            __builtin_amdgcn_s_setprio(1);
            #pragma unroll
            for (int u = 0; u < 2; u++) {
                int j = (jp << 1) | u;
                #pragma unroll
                for (int i = 0; i < 4; i++) {
                    acc[i][j] = __builtin_amdgcn_mfma_f32_16x16x32_bf16(ah[i], bh[u], acc[i][j], 0, 0, 0);
                    acc[i][j] = __builtin_amdgcn_mfma_f32_16x16x32_bf16(al[i], bh[u], acc[i][j], 0, 0, 0);
                    acc[i][j] = __builtin_amdgcn_mfma_f32_16x16x32_bf16(ah[i], bl[u], acc[i][j], 0, 0, 0);
                }
            }
            __builtin_amdgcn_s_setprio(0);
        }

        if (ss + 1 < NS) write_stage(lds + (((ss + 1) & 1) << 16));
        __syncthreads();
    }

    // dump per-group partial G' (each 128x128 fp32); C/D layout: col = lane&15, row = quad*4 + reg
    float* G0 = (float*)lds;
    float* G1 = (float*)(lds + 65536);
    {
        float* myG = grp ? G1 : G0;
        #pragma unroll
        for (int i = 0; i < 4; i++)
            #pragma unroll
            for (int j = 0; j < 4; j++)
                #pragma unroll
                for (int r = 0; r < 4; r++)
                    myG[(wr + (i << 4) + (quad << 2) + r) * 128 + wc2 + (j << 4) + lr] = acc[i][j][r];
    }
    __syncthreads();

    // epilogue: G' cols are 4*jl + gate ; reduce the two k-half partials here
    int jl = tid & 31;
    int rbase = tid >> 5;
    #pragma unroll
    for (int it = 0; it < 8; it++) {
        int row = rbase + (it << 4);
        f32x4 g0 = *(const f32x4*)(G0 + row * 128 + (jl << 2));
        f32x4 g1 = *(const f32x4*)(G1 + row * 128 + (jl << 2));
        float gi = g0[0] + g1[0] + biasT[(jl << 2) + 0];
        float gf = g0[1] + g1[1] + biasT[(jl << 2) + 1];
        float gg = g0[2] + g1[2] + biasT[(jl << 2) + 2];
        float go = g0[3] + g1[3] + biasT[(jl << 2) + 3];
        float si = fast_sigmoid(gi);
        float sf = fast_sigmoid(gf);
        float so = fast_sigmoid(go);
        int n = n0 + row;
        float cn = sf * creg[it] + si * fast_tanh(gg);
        creg[it] = cn;
        float h = so * fast_tanh(cn);
        u16 hh2, hl2; split2(h, hh2, hl2);
        size_t ho = (((size_t)ct * 1024 + n) << 5) + jl;
        oHhi[ho] = hh2; oHlo[ho] = hl2;
        if (oF32) oF32[((size_t)n << 9) + (ct << 5) + jl] = h;
    }
}

// Persistent cooperative kernel: one launch, T_SEQ+1 iterations, grid.sync per step.
// blocks 0..127: L1 engine (computes L1(t-1)); blocks 128..255: L0 engine (L0(t)).
__global__ __launch_bounds__(512, 2) void k_lstm_persist(
    const float* __restrict__ data,
    const u16* __restrict__ W0hi, const u16* __restrict__ W0lo,
    const u16* __restrict__ W1hi, const u16* __restrict__ W1lo,
    const float* __restrict__ b0, const float* __restrict__ b1,
    u16* __restrict__ h0hi, u16* __restrict__ h0lo,
    u16* __restrict__ h1hi, u16* __restrict__ h1lo,
    float* __restrict__ bfeat)
{
    cg::grid_group grid = cg::this_grid();
    __shared__ __align__(16) char lds[131072];   // 128KB: dbuf stage / G' halves (1 block/CU)
    __shared__ float biasT[128];

    int local_blk = blockIdx.x & 127;
    bool isL1 = blockIdx.x < 128;
    // XCD swizzle: same-XCD blocks share 2 col-tiles -> W slice stays L2-resident
    int ct = ((blockIdx.x & 7) << 1) | ((local_blk >> 6) & 1);  // 0..15
    int n0 = ((local_blk >> 3) & 7) << 7;                       // 0..896

    const float* bias = isL1 ? b1 : b0;
    if (threadIdx.x < 128)
        biasT[threadIdx.x] = bias[((threadIdx.x & 3) << 9) + (ct << 5) + (threadIdx.x >> 2)];
    __syncthreads();

    float creg[8];
    #pragma unroll
    for (int i = 0; i < 8; i++) creg[i] = 0.f;

    for (int t = 0; t <= T_SEQ; t++) {
        if (isL1) {
            if (t > 0) {
                int s = t - 1;
                const u16* xh = h0hi + (size_t)(s & 1) * HSLOT;
                const u16* xl = h0lo + (size_t)(s & 1) * HSLOT;
                const u16* hh = h1hi + (size_t)((s - 1) & 1) * HSLOT;
                const u16* hl = h1lo + (size_t)((s - 1) & 1) * HSLOT;
                u16* oh = h1hi + (size_t)(s & 1) * HSLOT;
                u16* ol = h1lo + (size_t)(s & 1) * HSLOT;
                lstm_tile_body(ct, n0, nullptr, xh, xl, 16, hh, hl,
                               W1hi, W1lo, NT1, creg, oh, ol,
                               (s == T_SEQ - 1) ? bfeat : nullptr, lds, biasT);
            }
        } else {
            if (t < T_SEQ) {
                const u16* hh = h0hi + (size_t)((t - 1) & 1) * HSLOT;
                const u16* hl = h0lo + (size_t)((t - 1) & 1) * HSLOT;
                u16* oh = h0hi + (size_t)(t & 1) * HSLOT;
                u16* ol = h0lo + (size_t)(t & 1) * HSLOT;
                lstm_tile_body(ct, n0, data + (size_t)t * C_IN, nullptr, nullptr, 4,
                               hh, hl, W0hi, W0lo, NT0, creg, oh, ol,
                               nullptr, lds, biasT);
            }
        }
        __threadfence();   // release h-writes to device scope before the barrier
        grid.sync();       // cross-XCD visibility handled by cooperative sync
    }
}

// ---------- heads + losses ----------
__global__ __launch_bounds__(64) void k_head(
    const float* __restrict__ hfeat, const float* __restrict__ Wcls, const float* __restrict__ bcls,
    const float* __restrict__ Wbb, const float* __restrict__ bbb,
    const int* __restrict__ labels, const float* __restrict__ props,
    float* __restrict__ accum)
{
    __shared__ float hs[H_DIM];
    __shared__ float logits[NCLS];
    __shared__ float bb[2];
    int n = blockIdx.x, t = threadIdx.x;
    for (int k = t; k < H_DIM; k += 64) hs[k] = hfeat[((size_t)n << 9) + k];
    __syncthreads();
    if (t < NCLS) {
        float s = bcls[t];
        const float* w = Wcls + (size_t)t * H_DIM;
        for (int k = 0; k < H_DIM; k++) s += hs[k] * w[k];
        logits[t] = s;
    } else if (t < NCLS + 2) {
        int j = t - NCLS;
        float s = bbb[j];
        const float* w = Wbb + (size_t)j * H_DIM;
        for (int k = 0; k < H_DIM; k++) s += hs[k] * w[k];
        bb[j] = s;
    }
    __syncthreads();
    if (t == 0) {
        float m = logits[0]; int am = 0;
        for (int j = 1; j < NCLS; j++) if (logits[j] > m) { m = logits[j]; am = j; }
        float se = 0.f;
        for (int j = 0; j < NCLS; j++) se += expf(logits[j] - m);
        int lbl = labels[n * 2];
        float logp = logits[lbl] - m - logf(se);
        atomicAdd(&accum[0], -logp);
        if (am == lbl) atomicAdd(&accum[1], 1.0f);
        float s2 = 0.f;
        for (int j = 0; j < 2; j++) {
            float target = props[n * 2 + j] * (1.0f / 256.0f);
            float d = fabsf(bb[j] - target);
            s2 += (d < 1.f) ? 0.5f * d * d : d - 0.5f;
        }
        atomicAdd(&accum[2], s2);
    }
}

__global__ void k_final(const float* __restrict__ accum, float* __restrict__ out) {
    out[0] = (accum[0] * (1.0f / 1024.0f)) / (1.0f + accum[1]);
    out[1] = accum[2] * (10.0f / 2048.0f);
}

// ---------- launch ----------
extern "C" void kernel_launch(void* const* d_in, const int* in_sizes, int n_in,
                              void* d_out, int out_size, void* d_ws, size_t ws_size,
                              hipStream_t stream) {
    const float* data  = (const float*)d_in[0];
    const int*   labels= (const int*)d_in[1];
    const float* props = (const float*)d_in[2];
    const float* Wih0  = (const float*)d_in[3];
    const float* Whh0  = (const float*)d_in[4];
    const float* b0    = (const float*)d_in[5];
    const float* Wih1  = (const float*)d_in[6];
    const float* Whh1  = (const float*)d_in[7];
    const float* b1    = (const float*)d_in[8];
    const float* Wcls  = (const float*)d_in[9];
    const float* bcls  = (const float*)d_in[10];
    const float* Wbb   = (const float*)d_in[11];
    const float* bbb   = (const float*)d_in[12];
    float* out = (float*)d_out;

    char* ws = (char*)d_ws;
    size_t off = 0;
    auto alloc = [&](size_t bytes) -> void* {
        void* p = ws + off;
        off = (off + bytes + 255) & ~(size_t)255;
        return p;
    };
    const size_t NH = (size_t)N_B * H_DIM;
    const size_t W0E = (size_t)16 * NT0 * 128 * 32;   // 1,310,720
    const size_t W1E = (size_t)16 * NT1 * 128 * 32;   // 2,097,152

    u16* W0hi = (u16*)alloc(W0E * 2);
    u16* W0lo = (u16*)alloc(W0E * 2);
    u16* W1hi = (u16*)alloc(W1E * 2);
    u16* W1lo = (u16*)alloc(W1E * 2);
    u16* h0hi = (u16*)alloc(2 * (size_t)HSLOT * 2);
    u16* h0lo = (u16*)alloc(2 * (size_t)HSLOT * 2);
    u16* h1hi = (u16*)alloc(2 * (size_t)HSLOT * 2);
    u16* h1lo = (u16*)alloc(2 * (size_t)HSLOT * 2);
    float* bfeat= (float*)alloc(NH * 4);
    float* accum= (float*)alloc(4 * 4);

    k_pack_w<<<(int)(W0E / 256), 256, 0, stream>>>(Wih0, Whh0, C_IN, NT0, W0hi, W0lo);
    k_pack_w<<<(int)(W1E / 256), 256, 0, stream>>>(Wih1, Whh1, H_DIM, NT1, W1hi, W1lo);

    (void)hipMemsetAsync(h0hi + HSLOT, 0, (size_t)HSLOT * 2, stream);
    (void)hipMemsetAsync(h0lo + HSLOT, 0, (size_t)HSLOT * 2, stream);
    (void)hipMemsetAsync(h1hi + HSLOT, 0, (size_t)HSLOT * 2, stream);
    (void)hipMemsetAsync(h1lo + HSLOT, 0, (size_t)HSLOT * 2, stream);
    (void)hipMemsetAsync(accum, 0, 16, stream);

    {
        const float* a_data = data;
        const u16* a_W0hi = W0hi; const u16* a_W0lo = W0lo;
        const u16* a_W1hi = W1hi; const u16* a_W1lo = W1lo;
        const float* a_b0 = b0;   const float* a_b1 = b1;
        u16* a_h0hi = h0hi; u16* a_h0lo = h0lo;
        u16* a_h1hi = h1hi; u16* a_h1lo = h1lo;
        float* a_bfeat = bfeat;
        void* kargs[] = {
            (void*)&a_data,
            (void*)&a_W0hi, (void*)&a_W0lo,
            (void*)&a_W1hi, (void*)&a_W1lo,
            (void*)&a_b0, (void*)&a_b1,
            (void*)&a_h0hi, (void*)&a_h0lo,
            (void*)&a_h1hi, (void*)&a_h1lo,
            (void*)&a_bfeat
        };
        (void)hipLaunchCooperativeKernel((const void*)k_lstm_persist,
                                         dim3(256), dim3(512), kargs, 0, stream);
    }

    k_head<<<N_B, 64, 0, stream>>>(bfeat, Wcls, bcls, Wbb, bbb, labels, props, accum);
    k_final<<<1, 1, 0, stream>>>(accum, out);
}

// Round 4
// 7187.714 us; speedup vs baseline: 3.7593x; 3.7593x over previous
//
#include <hip/hip_runtime.h>

typedef unsigned short u16;
typedef __attribute__((ext_vector_type(8))) __bf16 bf16x8;
typedef __attribute__((ext_vector_type(4))) float f32x4;

#define T_SEQ 256
#define N_B   1024
#define C_IN  128
#define H_DIM 512
#define NCLS  40
#define NT0   20
#define NT1   32
#define HSLOT (16*1024*32)   // u16 elems per hpack slot

union B8 { bf16x8 v; u16 s[8]; };

// ---------- bf16 split helpers ----------
__device__ __forceinline__ u16 f32_to_bf16_rne(float x) {
    unsigned u = __float_as_uint(x);
    unsigned rounding = 0x7FFFu + ((u >> 16) & 1u);
    return (u16)((u + rounding) >> 16);
}
__device__ __forceinline__ float bf16_to_f32(u16 h) {
    return __uint_as_float(((unsigned)h) << 16);
}
__device__ __forceinline__ void split2(float x, u16& hi, u16& lo) {
    u16 h = f32_to_bf16_rne(x);
    float hf = bf16_to_f32(h);
    u16 l = f32_to_bf16_rne(x - hf);
    hi = h; lo = l;
}
__device__ __forceinline__ float fast_sigmoid(float x) {
    return 1.0f / (1.0f + __expf(-x));
}
__device__ __forceinline__ float fast_tanh(float x) {
    return 1.0f - 2.0f / (__expf(2.0f * x) + 1.0f);
}

// async global->LDS, 16B per lane; LDS dest is wave-uniform base + lane*16
__device__ __forceinline__ void glds16(const void* g, void* l) {
    __builtin_amdgcn_global_load_lds(
        (const __attribute__((address_space(1))) void*)(unsigned long long)(g),
        (__attribute__((address_space(3))) void*)(unsigned int)(unsigned long long)(l),
        16, 0, 0);
}

// ---------- prep: pack W into per-(ct,kt) fragment blocks ----------
// layout: idx = ((ct*NT + kt)*128 + r)*32 + k ; r = 4*jl + gate
__global__ void k_pack_w(const float* __restrict__ Wih, const float* __restrict__ Whh,
                         int KX, int NT, u16* __restrict__ hi, u16* __restrict__ lo) {
    size_t idx = (size_t)blockIdx.x * 256 + threadIdx.x;
    size_t total = (size_t)16 * NT * 128 * 32;
    if (idx >= total) return;
    int k = (int)(idx & 31);
    int r = (int)((idx >> 5) & 127);
    int rem = (int)(idx >> 12);
    int kt = rem % NT, ct = rem / NT;
    int gate = r & 3, jl = r >> 2;
    int srow = (gate << 9) + (ct << 5) + jl;
    int kg = (kt << 5) + k;
    float v = (kg < KX) ? Wih[(size_t)srow * KX + kg] : Whh[(size_t)srow * H_DIM + (kg - KX)];
    u16 h, l; split2(v, h, l);
    hi[idx] = h; lo[idx] = l;
}

// ---------- LSTM step tile body ----------
// block = 128 batch x 128 G'-cols, 8 waves.
// BK=64 super-steps: waves 0-3 (grp 0) compute even k-tiles, waves 4-7 (grp 1)
// odd k-tiles; each wave owns a 64x64 output tile (4x4 acc).  Partials reduced
// through two 64KB G' halves in LDS at the end.
// Staging: W and hpack-A via global_load_lds (async, no VGPR roundtrip);
// L0's fp32 X (kt<nxt) reg-staged + converted + ds_write.
// Stage buffer layout (64KB per super-step, double-buffered = 128KB):
//   +0      A_hi[sub0]  +8192   A_hi[sub1]
//   +16384  A_lo[sub0]  +24576  A_lo[sub1]
//   +32768  B_hi[sub0]  +40960  B_hi[sub1]
//   +49152  B_lo[sub0]  +57344  B_lo[sub1]
__device__ __forceinline__ void lstm_tile_body(
    int local_blk,
    const float* __restrict__ Xf32,                       // L0: data + t*C (row stride 32768), else null
    const u16* __restrict__ xAhi, const u16* __restrict__ xAlo, int nxt,
    const u16* __restrict__ hAhi, const u16* __restrict__ hAlo,
    const u16* __restrict__ Whi, const u16* __restrict__ Wlo, int NT,
    const float* __restrict__ bias, float* __restrict__ cbuf,
    u16* __restrict__ oHhi, u16* __restrict__ oHlo, float* __restrict__ oF32,
    char* lds, float* biasT)
{
    // XCD swizzle: same-XCD blocks share 2 col-tiles -> W slice stays L2-resident
    int ct = ((blockIdx.x & 7) << 1) | ((local_blk >> 6) & 1);  // 0..15
    int rt = (local_blk >> 3) & 7;                              // 0..7
    int n0 = rt << 7;

    int tid  = threadIdx.x;
    int w    = tid >> 6;
    int l    = tid & 63;
    int quad = l >> 4;
    int lr   = l & 15;
    int grp  = w >> 2;              // 0: even k-tiles, 1: odd k-tiles
    int wr   = (w & 1) << 6;        // 0 or 64
    int wc2  = ((w >> 1) & 1) << 6; // 0 or 64

    if (tid < 128)
        biasT[tid] = bias[((tid & 3) << 9) + (ct << 5) + (tid >> 2)];

    const size_t wbase = ((size_t)(ct * NT)) << 12;
    bf16x8 sxh[2], sxl[2];   // X-path staging regs (L0 kt<nxt only)

    // async staging of W (always) and hpack-A (when not X-sourced)
    auto stage_ss = [&](int ss, char* buf) {
        #pragma unroll
        for (int g = 0; g < 2; g++) {
            int kt = (ss << 1) | g;
            char* wavebase = buf + (g << 13) + ((tid >> 6) << 10);
            size_t wo = wbase + ((size_t)kt << 12) + ((size_t)tid << 3);
            glds16(Whi + wo, wavebase + 32768);
            glds16(Wlo + wo, wavebase + 49152);
            if (Xf32 == nullptr || kt >= nxt) {
                const u16 *ph, *pl; int kk;
                if (kt < nxt) { ph = xAhi; pl = xAlo; kk = kt; }
                else          { ph = hAhi; pl = hAlo; kk = kt - nxt; }
                size_t ao = (((size_t)kk * 1024 + n0) << 5) + ((size_t)tid << 3);
                glds16(ph + ao, wavebase);
                glds16(pl + ao, wavebase + 16384);
            }
        }
    };
    auto loadX = [&](int ss) {
        #pragma unroll
        for (int g = 0; g < 2; g++) {
            int kt = (ss << 1) | g;
            int row = tid >> 2, seg = tid & 3;
            const float* p = Xf32 + (size_t)(n0 + row) * 32768 + (kt << 5) + (seg << 3);
            f32x4 x0 = *(const f32x4*)p;
            f32x4 x1 = *(const f32x4*)(p + 4);
            B8 hh, ll;
            #pragma unroll
            for (int e = 0; e < 4; e++) { u16 a, b; split2(x0[e], a, b); hh.s[e] = a; ll.s[e] = b; }
            #pragma unroll
            for (int e = 0; e < 4; e++) { u16 a, b; split2(x1[e], a, b); hh.s[4 + e] = a; ll.s[4 + e] = b; }
            sxh[g] = hh.v; sxl[g] = ll.v;
        }
    };
    auto writeX = [&](char* buf) {
        #pragma unroll
        for (int g = 0; g < 2; g++) {
            char* p = buf + (g << 13) + (tid << 4);
            *(bf16x8*)(p)         = sxh[g];
            *(bf16x8*)(p + 16384) = sxl[g];
        }
    };

    f32x4 acc[4][4];
    #pragma unroll
    for (int i = 0; i < 4; i++)
        #pragma unroll
        for (int j = 0; j < 4; j++)
            acc[i][j] = (f32x4){0.f, 0.f, 0.f, 0.f};

    const int NS = NT >> 1;
    stage_ss(0, lds);
    if (Xf32 != nullptr) { loadX(0); writeX(lds); }
    __syncthreads();

    for (int ss = 0; ss < NS; ss++) {
        char* buf  = lds + ((ss & 1) << 16);
        char* cur  = buf + (grp << 13);
        char* nbuf = lds + (((ss + 1) & 1) << 16);
        bool pf  = (ss + 1 < NS);
        bool pfX = pf && (Xf32 != nullptr) && (((ss + 1) << 1) < nxt);
        if (pf) stage_ss(ss + 1, nbuf);
        if (pfX) loadX(ss + 1);

        bf16x8 ah[4], al[4];
        #pragma unroll
        for (int i = 0; i < 4; i++) {
            int ro = ((wr + (i << 4) + lr) << 6) + (quad << 4);
            ah[i] = *(const bf16x8*)(cur + ro);
            al[i] = *(const bf16x8*)(cur + 16384 + ro);
        }
        #pragma unroll
        for (int jp = 0; jp < 2; jp++) {
            bf16x8 bh[2], bl[2];
            #pragma unroll
            for (int u = 0; u < 2; u++) {
                int j = (jp << 1) | u;
                int ro = ((wc2 + (j << 4) + lr) << 6) + (quad << 4);
                bh[u] = *(const bf16x8*)(cur + 32768 + ro);
                bl[u] = *(const bf16x8*)(cur + 49152 + ro);
            }
            __builtin_amdgcn_s_setprio(1);
            #pragma unroll
            for (int u = 0; u < 2; u++) {
                int j = (jp << 1) | u;
                #pragma unroll
                for (int i = 0; i < 4; i++) {
                    acc[i][j] = __builtin_amdgcn_mfma_f32_16x16x32_bf16(ah[i], bh[u], acc[i][j], 0, 0, 0);
                    acc[i][j] = __builtin_amdgcn_mfma_f32_16x16x32_bf16(al[i], bh[u], acc[i][j], 0, 0, 0);
                    acc[i][j] = __builtin_amdgcn_mfma_f32_16x16x32_bf16(ah[i], bl[u], acc[i][j], 0, 0, 0);
                }
            }
            __builtin_amdgcn_s_setprio(0);
        }

        if (pfX) writeX(nbuf);
        __syncthreads();
    }

    // dump per-group partial G' (each 128x128 fp32); C/D layout: col = lane&15, row = quad*4 + reg
    // col XOR-swizzled by ((row>>2)&3)<<2 -> store-side bank-conflict-free
    float* G0 = (float*)lds;
    float* G1 = (float*)(lds + 65536);
    {
        float* myG = grp ? G1 : G0;
        #pragma unroll
        for (int i = 0; i < 4; i++)
            #pragma unroll
            for (int j = 0; j < 4; j++)
                #pragma unroll
                for (int r = 0; r < 4; r++) {
                    int rr = wr + (i << 4) + (quad << 2) + r;
                    int col = wc2 + (j << 4) + lr;
                    myG[rr * 128 + (col ^ (((rr >> 2) & 3) << 2))] = acc[i][j][r];
                }
    }
    __syncthreads();

    // epilogue: G' cols are 4*jl + gate ; reduce the two k-half partials here
    int jl = tid & 31;
    int rbase = tid >> 5;
    #pragma unroll
    for (int it = 0; it < 8; it++) {
        int row = rbase + (it << 4);
        int cS = (jl << 2) ^ (((row >> 2) & 3) << 2);
        f32x4 g0 = *(const f32x4*)(G0 + row * 128 + cS);
        f32x4 g1 = *(const f32x4*)(G1 + row * 128 + cS);
        float gi = g0[0] + g1[0] + biasT[(jl << 2) + 0];
        float gf = g0[1] + g1[1] + biasT[(jl << 2) + 1];
        float gg = g0[2] + g1[2] + biasT[(jl << 2) + 2];
        float go = g0[3] + g1[3] + biasT[(jl << 2) + 3];
        float si = fast_sigmoid(gi);
        float sf = fast_sigmoid(gf);
        float so = fast_sigmoid(go);
        int n = n0 + row;
        int cidx = (n << 9) + (ct << 5) + jl;
        float cn = sf * cbuf[cidx] + si * fast_tanh(gg);
        cbuf[cidx] = cn;
        float h = so * fast_tanh(cn);
        u16 hh2, hl2; split2(h, hh2, hl2);
        size_t ho = (((size_t)ct * 1024 + n) << 5) + jl;
        oHhi[ho] = hh2; oHlo[ho] = hl2;
        if (oF32) oF32[cidx] = h;
    }
}

// blocks 0..127: L1(t-1); blocks 128..255: L0(t)
__global__ __launch_bounds__(512) void k_lstm_pair(
    int t, const float* __restrict__ data,
    const u16* __restrict__ W0hi, const u16* __restrict__ W0lo,
    const u16* __restrict__ W1hi, const u16* __restrict__ W1lo,
    const float* __restrict__ b0, const float* __restrict__ b1,
    u16* __restrict__ h0hi, u16* __restrict__ h0lo,
    u16* __restrict__ h1hi, u16* __restrict__ h1lo,
    float* __restrict__ c0, float* __restrict__ c1,
    float* __restrict__ bfeat)
{
    __shared__ __align__(16) char lds[131072];   // 128KB: dbuf stage / G' halves (1 block/CU)
    __shared__ float biasT[128];
    int local_blk = blockIdx.x & 127;

    if (blockIdx.x < 128) {
        if (t == 0) return;
        int s = t - 1;
        const u16* xh = h0hi + (size_t)(s & 1) * HSLOT;
        const u16* xl = h0lo + (size_t)(s & 1) * HSLOT;
        const u16* hh = h1hi + (size_t)((s - 1) & 1) * HSLOT;
        const u16* hl = h1lo + (size_t)((s - 1) & 1) * HSLOT;
        u16* oh = h1hi + (size_t)(s & 1) * HSLOT;
        u16* ol = h1lo + (size_t)(s & 1) * HSLOT;
        lstm_tile_body(local_blk, nullptr, xh, xl, 16, hh, hl,
                       W1hi, W1lo, NT1, b1, c1, oh, ol,
                       (s == T_SEQ - 1) ? bfeat : nullptr, lds, biasT);
    } else {
        if (t >= T_SEQ) return;
        const u16* hh = h0hi + (size_t)((t - 1) & 1) * HSLOT;
        const u16* hl = h0lo + (size_t)((t - 1) & 1) * HSLOT;
        u16* oh = h0hi + (size_t)(t & 1) * HSLOT;
        u16* ol = h0lo + (size_t)(t & 1) * HSLOT;
        lstm_tile_body(local_blk, data + (size_t)t * C_IN, nullptr, nullptr, 4,
                       hh, hl, W0hi, W0lo, NT0, b0, c0, oh, ol,
                       nullptr, lds, biasT);
    }
}

// ---------- heads + losses ----------
__global__ __launch_bounds__(64) void k_head(
    const float* __restrict__ hfeat, const float* __restrict__ Wcls, const float* __restrict__ bcls,
    const float* __restrict__ Wbb, const float* __restrict__ bbb,
    const int* __restrict__ labels, const float* __restrict__ props,
    float* __restrict__ accum)
{
    __shared__ float hs[H_DIM];
    __shared__ float logits[NCLS];
    __shared__ float bb[2];
    int n = blockIdx.x, t = threadIdx.x;
    for (int k = t; k < H_DIM; k += 64) hs[k] = hfeat[((size_t)n << 9) + k];
    __syncthreads();
    if (t < NCLS) {
        float s = bcls[t];
        const float* w = Wcls + (size_t)t * H_DIM;
        for (int k = 0; k < H_DIM; k++) s += hs[k] * w[k];
        logits[t] = s;
    } else if (t < NCLS + 2) {
        int j = t - NCLS;
        float s = bbb[j];
        const float* w = Wbb + (size_t)j * H_DIM;
        for (int k = 0; k < H_DIM; k++) s += hs[k] * w[k];
        bb[j] = s;
    }
    __syncthreads();
    if (t == 0) {
        float m = logits[0]; int am = 0;
        for (int j = 1; j < NCLS; j++) if (logits[j] > m) { m = logits[j]; am = j; }
        float se = 0.f;
        for (int j = 0; j < NCLS; j++) se += expf(logits[j] - m);
        int lbl = labels[n * 2];
        float logp = logits[lbl] - m - logf(se);
        atomicAdd(&accum[0], -logp);
        if (am == lbl) atomicAdd(&accum[1], 1.0f);
        float s2 = 0.f;
        for (int j = 0; j < 2; j++) {
            float target = props[n * 2 + j] * (1.0f / 256.0f);
            float d = fabsf(bb[j] - target);
            s2 += (d < 1.f) ? 0.5f * d * d : d - 0.5f;
        }
        atomicAdd(&accum[2], s2);
    }
}

__global__ void k_final(const float* __restrict__ accum, float* __restrict__ out) {
    out[0] = (accum[0] * (1.0f / 1024.0f)) / (1.0f + accum[1]);
    out[1] = accum[2] * (10.0f / 2048.0f);
}

// ---------- launch ----------
extern "C" void kernel_launch(void* const* d_in, const int* in_sizes, int n_in,
                              void* d_out, int out_size, void* d_ws, size_t ws_size,
                              hipStream_t stream) {
    const float* data  = (const float*)d_in[0];
    const int*   labels= (const int*)d_in[1];
    const float* props = (const float*)d_in[2];
    const float* Wih0  = (const float*)d_in[3];
    const float* Whh0  = (const float*)d_in[4];
    const float* b0    = (const float*)d_in[5];
    const float* Wih1  = (const float*)d_in[6];
    const float* Whh1  = (const float*)d_in[7];
    const float* b1    = (const float*)d_in[8];
    const float* Wcls  = (const float*)d_in[9];
    const float* bcls  = (const float*)d_in[10];
    const float* Wbb   = (const float*)d_in[11];
    const float* bbb   = (const float*)d_in[12];
    float* out = (float*)d_out;

    char* ws = (char*)d_ws;
    size_t off = 0;
    auto alloc = [&](size_t bytes) -> void* {
        void* p = ws + off;
        off = (off + bytes + 255) & ~(size_t)255;
        return p;
    };
    const size_t NH = (size_t)N_B * H_DIM;
    const size_t W0E = (size_t)16 * NT0 * 128 * 32;   // 1,310,720
    const size_t W1E = (size_t)16 * NT1 * 128 * 32;   // 2,097,152

    u16* W0hi = (u16*)alloc(W0E * 2);
    u16* W0lo = (u16*)alloc(W0E * 2);
    u16* W1hi = (u16*)alloc(W1E * 2);
    u16* W1lo = (u16*)alloc(W1E * 2);
    u16* h0hi = (u16*)alloc(2 * (size_t)HSLOT * 2);
    u16* h0lo = (u16*)alloc(2 * (size_t)HSLOT * 2);
    u16* h1hi = (u16*)alloc(2 * (size_t)HSLOT * 2);
    u16* h1lo = (u16*)alloc(2 * (size_t)HSLOT * 2);
    float* c0   = (float*)alloc(NH * 4);
    float* c1   = (float*)alloc(NH * 4);
    float* bfeat= (float*)alloc(NH * 4);
    float* accum= (float*)alloc(4 * 4);

    k_pack_w<<<(int)(W0E / 256), 256, 0, stream>>>(Wih0, Whh0, C_IN, NT0, W0hi, W0lo);
    k_pack_w<<<(int)(W1E / 256), 256, 0, stream>>>(Wih1, Whh1, H_DIM, NT1, W1hi, W1lo);

    (void)hipMemsetAsync(h0hi + HSLOT, 0, (size_t)HSLOT * 2, stream);
    (void)hipMemsetAsync(h0lo + HSLOT, 0, (size_t)HSLOT * 2, stream);
    (void)hipMemsetAsync(h1hi + HSLOT, 0, (size_t)HSLOT * 2, stream);
    (void)hipMemsetAsync(h1lo + HSLOT, 0, (size_t)HSLOT * 2, stream);
    (void)hipMemsetAsync(c0, 0, NH * 4, stream);
    (void)hipMemsetAsync(c1, 0, NH * 4, stream);
    (void)hipMemsetAsync(accum, 0, 16, stream);

    for (int t = 0; t <= T_SEQ; t++) {
        k_lstm_pair<<<256, 512, 0, stream>>>(
            t, data, W0hi, W0lo, W1hi, W1lo, b0, b1,
            h0hi, h0lo, h1hi, h1lo, c0, c1, bfeat);
    }

    k_head<<<N_B, 64, 0, stream>>>(bfeat, Wcls, bcls, Wbb, bbb, labels, props, accum);
    k_final<<<1, 1, 0, stream>>>(accum, out);
}